// Round 9
// baseline (219.940 us; speedup 1.0000x reference)
//
#include <hip/hip_runtime.h>
#include <hip/hip_fp16.h>

#define N_NODES 100000
#define N_EDGES 1200000

#define BIN_SHIFT 6
#define NODES_PER_BIN 64                       // 1 << BIN_SHIFT
#define NBINS ((N_NODES + NODES_PER_BIN - 1) >> BIN_SHIFT)   // 1563
#define CAP 1024                               // max edges per bucket (mean 768, max ~906)
#define EPB 8192                               // edges per binning block
#define NBLK_BIN ((N_EDGES + EPB - 1) / EPB)   // 147

// ---------------- binning: edges -> fixed-stride bucket regions ----------------
// packed word: src (bits 0..16) | (dst & 63) << 17
__global__ void binning_kernel(const int* __restrict__ src, const int* __restrict__ dst,
                               int* __restrict__ gcursor, unsigned int* __restrict__ binned,
                               int E) {
    __shared__ unsigned int stage[EPB];      // 32 KB
    __shared__ unsigned short sbin[EPB];     // 16 KB
    __shared__ unsigned int hist[NBINS];     // ~6.3 KB
    int t = threadIdx.x;
    int e_base = blockIdx.x * EPB;

    for (int b = t; b < NBINS; b += 256) hist[b] = 0;
    __syncthreads();

#pragma unroll
    for (int j = 0; j < EPB / 256; ++j) {
        int idx = e_base + t + j * 256;
        if (idx < E) {
            int s = src[idx];
            int d = dst[idx];
            unsigned int bin = (unsigned int)d >> BIN_SHIFT;
            stage[t + j * 256] = (unsigned int)s | (((unsigned int)d & 63u) << 17);
            sbin[t + j * 256] = (unsigned short)bin;
            atomicAdd(&hist[bin], 1u);
        }
    }
    __syncthreads();

    for (int b = t; b < NBINS; b += 256) {
        unsigned int c = hist[b];
        if (c) hist[b] = (unsigned int)(b * CAP) + (unsigned int)atomicAdd(&gcursor[b], (int)c);
    }
    __syncthreads();

#pragma unroll
    for (int j = 0; j < EPB / 256; ++j) {
        int idx = e_base + t + j * 256;
        if (idx < E) {
            unsigned int bin = sbin[t + j * 256];
            unsigned int pos = atomicAdd(&hist[bin], 1u);
            binned[pos] = stage[t + j * 256];
        }
    }
}

// ---------------- csr: per-bucket degree count -> dinv, CSR-sort srcs in place,
//                  emit offdeg[node] = (local_off << 16) | deg ----------------
__global__ void csr_kernel(unsigned int* __restrict__ binned,
                           const int* __restrict__ gcursor,
                           float* __restrict__ dinv,
                           unsigned int* __restrict__ offdeg) {
    __shared__ unsigned int eLDS[CAP];
    __shared__ unsigned int counts[NODES_PER_BIN];
    __shared__ unsigned int scan[NODES_PER_BIN];
    __shared__ unsigned int offs[NODES_PER_BIN];
    __shared__ unsigned int cur[NODES_PER_BIN];
    int bin = blockIdx.x;
    int t = threadIdx.x;
    int nb = gcursor[bin];
    unsigned int* eb = binned + (size_t)bin * CAP;

    if (t < NODES_PER_BIN) counts[t] = 0;
    __syncthreads();
    for (int i = t; i < nb; i += 256) {
        unsigned int p = eb[i];
        eLDS[i] = p;
        atomicAdd(&counts[p >> 17], 1u);
    }
    __syncthreads();
    if (t < NODES_PER_BIN) scan[t] = counts[t];
    __syncthreads();
    for (int step = 1; step < NODES_PER_BIN; step <<= 1) {
        unsigned int v = 0;
        if (t < NODES_PER_BIN && t >= step) v = scan[t - step];
        __syncthreads();
        if (t < NODES_PER_BIN) scan[t] += v;
        __syncthreads();
    }
    if (t < NODES_PER_BIN) {
        offs[t] = scan[t] - counts[t];
        cur[t] = 0;
    }
    __syncthreads();
    // CSR-order srcs written back into the SAME bin region (fully staged in LDS above)
    for (int i = t; i < nb; i += 256) {
        unsigned int p = eLDS[i];
        unsigned int l = p >> 17;
        unsigned int pos = offs[l] + atomicAdd(&cur[l], 1u);
        eb[pos] = p & 0x1FFFFu;
    }
    if (t < NODES_PER_BIN) {
        int node = bin * NODES_PER_BIN + t;
        if (node < N_NODES) {
            dinv[node] = rsqrtf((float)(counts[t] + 1u));
            offdeg[node] = (offs[t] << 16) | counts[t];
        }
    }
}

// ---------------- register-tiled skinny GEMM (64 rows/block) ----------------
// H[n,DOUT] = rowscale[r] * (X[n,64] @ W[64,DOUT]) (+bias)
// HALF_OUT: write fp16 (packed); else fp32.
template<int DOUT, bool HALF_OUT>
__global__ __launch_bounds__(256, 4) void gemm_kernel(const float* __restrict__ X,
                                                      const float* __restrict__ W,
                                                      const float* __restrict__ bias,
                                                      const float* __restrict__ rowscale,
                                                      void* __restrict__ Hout, int n) {
    constexpr int COLG = DOUT / 4;       // 16 (d64) or 8 (d32)
    constexpr int RGS  = 256 / COLG;     // 16 or 32
    constexpr int RPT  = 64 / RGS;       // 4 or 2
    constexpr int XPITCH = 17;           // float4 pitch (bank-disjoint row reads)
    __shared__ float4 sW4[64 * COLG];
    __shared__ float4 sX4[64 * XPITCH];
    int tid = threadIdx.x;

    for (int i = tid; i < 64 * COLG; i += 256) sW4[i] = ((const float4*)W)[i];

    int base_row = blockIdx.x * 64;
    const float4* X4 = (const float4*)X;
    for (int i = tid; i < 64 * 16; i += 256) {
        int r = i >> 4, c = i & 15;
        int gr = base_row + r;
        float4 v = make_float4(0.f, 0.f, 0.f, 0.f);
        if (gr < n) v = X4[(size_t)gr * 16 + c];
        sX4[r * XPITCH + c] = v;
    }
    __syncthreads();

    int cg = tid % COLG;
    int rg = tid / COLG;
    float4 acc[RPT];
#pragma unroll
    for (int r = 0; r < RPT; ++r) acc[r] = make_float4(0.f, 0.f, 0.f, 0.f);

#pragma unroll 2
    for (int k4 = 0; k4 < 16; ++k4) {
        float4 xv[RPT];
#pragma unroll
        for (int r = 0; r < RPT; ++r) xv[r] = sX4[(rg + RGS * r) * XPITCH + k4];
#pragma unroll
        for (int kk = 0; kk < 4; ++kk) {
            float4 w = sW4[(k4 * 4 + kk) * COLG + cg];
#pragma unroll
            for (int r = 0; r < RPT; ++r) {
                float xs = (kk == 0) ? xv[r].x : (kk == 1) ? xv[r].y : (kk == 2) ? xv[r].z : xv[r].w;
                acc[r].x = fmaf(xs, w.x, acc[r].x);
                acc[r].y = fmaf(xs, w.y, acc[r].y);
                acc[r].z = fmaf(xs, w.z, acc[r].z);
                acc[r].w = fmaf(xs, w.w, acc[r].w);
            }
        }
    }

#pragma unroll
    for (int r = 0; r < RPT; ++r) {
        int grow = base_row + rg + RGS * r;
        if (grow < n) {
            float4 v = acc[r];
            if (rowscale) {
                float s = rowscale[grow];
                v.x *= s; v.y *= s; v.z *= s; v.w *= s;
            }
            if (bias) {
                float4 bb = ((const float4*)bias)[cg];
                v.x += bb.x; v.y += bb.y; v.z += bb.z; v.w += bb.w;
            }
            if (HALF_OUT) {
                __half2* H2 = (__half2*)Hout;
                size_t idx = (size_t)grow * (DOUT / 2) + 2 * cg;
                H2[idx]     = __floats2half2_rn(v.x, v.y);
                H2[idx + 1] = __floats2half2_rn(v.z, v.w);
            } else {
                ((float4*)Hout)[(size_t)grow * COLG + cg] = v;
            }
        }
    }
}

// ---------------- gather aggregation + epilogue (CSR pre-built) ----------------
// binned bin region now holds CSR-ordered src ids; offdeg[node] = off<<16|deg.
// tmp (fp16) rows pre-scaled by dinv[row]; h[v] = relu(dinv[v]*(tmp[v]+sum tmp[src])+b)
// 8 threads/node, 16 B (8 halves) per thread -> one 128 B line per edge.
__global__ void aggregate_kernel(const __half* __restrict__ tmp,
                                 const unsigned int* __restrict__ binned,
                                 const int* __restrict__ gcursor,
                                 const unsigned int* __restrict__ offdeg,
                                 const float* __restrict__ dinv,
                                 const float* __restrict__ b,
                                 float* __restrict__ h) {
    __shared__ unsigned int srcs[CAP];          // 4 KB
    __shared__ unsigned int sOffdeg[NODES_PER_BIN];
    __shared__ float sDinv[NODES_PER_BIN];
    int bin = blockIdx.x;
    int t = threadIdx.x;
    int nb = gcursor[bin];
    const unsigned int* eb = binned + (size_t)bin * CAP;

    if (t < NODES_PER_BIN) {
        int node = bin * NODES_PER_BIN + t;
        sOffdeg[t] = (node < N_NODES) ? offdeg[node] : 0;
        sDinv[t] = (node < N_NODES) ? dinv[node] : 0.0f;
    }
    for (int i = t; i < nb; i += 256) srcs[i] = eb[i];
    __syncthreads();

    int oct = t & 7;            // 16 B slice within the 128 B row
    int lnode0 = t >> 3;        // 0..31
    const uint4* tmp16 = (const uint4*)tmp;   // row = 8 uint4
    float bb[8];
    {
        const float4 b0 = ((const float4*)b)[oct * 2];
        const float4 b1 = ((const float4*)b)[oct * 2 + 1];
        bb[0] = b0.x; bb[1] = b0.y; bb[2] = b0.z; bb[3] = b0.w;
        bb[4] = b1.x; bb[5] = b1.y; bb[6] = b1.z; bb[7] = b1.w;
    }

#pragma unroll
    for (int g = 0; g < 2; ++g) {
        int ln = g * 32 + lnode0;
        int node = bin * NODES_PER_BIN + ln;
        if (node < N_NODES) {
            unsigned int od = sOffdeg[ln];
            int deg = (int)(od & 0xFFFFu);
            int beg = (int)(od >> 16);
            float acc[8];
            {
                uint4 raw = tmp16[(size_t)node * 8 + oct];   // self-loop term
                const __half2* hp = (const __half2*)&raw;
#pragma unroll
                for (int j = 0; j < 4; ++j) {
                    float2 f = __half22float2(hp[j]);
                    acc[2 * j] = f.x; acc[2 * j + 1] = f.y;
                }
            }
            int e = 0;
            for (; e + 3 < deg; e += 4) {       // 4 lines in flight
                unsigned int s0 = srcs[beg + e];
                unsigned int s1 = srcs[beg + e + 1];
                unsigned int s2 = srcs[beg + e + 2];
                unsigned int s3 = srcs[beg + e + 3];
                uint4 r0 = tmp16[(size_t)s0 * 8 + oct];
                uint4 r1 = tmp16[(size_t)s1 * 8 + oct];
                uint4 r2 = tmp16[(size_t)s2 * 8 + oct];
                uint4 r3 = tmp16[(size_t)s3 * 8 + oct];
                const __half2* h0 = (const __half2*)&r0;
                const __half2* h1 = (const __half2*)&r1;
                const __half2* h2 = (const __half2*)&r2;
                const __half2* h3 = (const __half2*)&r3;
#pragma unroll
                for (int j = 0; j < 4; ++j) {
                    float2 f0 = __half22float2(h0[j]);
                    float2 f1 = __half22float2(h1[j]);
                    float2 f2 = __half22float2(h2[j]);
                    float2 f3 = __half22float2(h3[j]);
                    acc[2 * j]     += (f0.x + f1.x) + (f2.x + f3.x);
                    acc[2 * j + 1] += (f0.y + f1.y) + (f2.y + f3.y);
                }
            }
            for (; e < deg; ++e) {
                unsigned int s0 = srcs[beg + e];
                uint4 r0 = tmp16[(size_t)s0 * 8 + oct];
                const __half2* h0 = (const __half2*)&r0;
#pragma unroll
                for (int j = 0; j < 4; ++j) {
                    float2 f0 = __half22float2(h0[j]);
                    acc[2 * j]     += f0.x;
                    acc[2 * j + 1] += f0.y;
                }
            }
            float dv = sDinv[ln];
            float4 o0, o1;
            o0.x = fmaxf(fmaf(dv, acc[0], bb[0]), 0.0f);
            o0.y = fmaxf(fmaf(dv, acc[1], bb[1]), 0.0f);
            o0.z = fmaxf(fmaf(dv, acc[2], bb[2]), 0.0f);
            o0.w = fmaxf(fmaf(dv, acc[3], bb[3]), 0.0f);
            o1.x = fmaxf(fmaf(dv, acc[4], bb[4]), 0.0f);
            o1.y = fmaxf(fmaf(dv, acc[5], bb[5]), 0.0f);
            o1.z = fmaxf(fmaf(dv, acc[6], bb[6]), 0.0f);
            o1.w = fmaxf(fmaf(dv, acc[7], bb[7]), 0.0f);
            float4* hv = (float4*)(h + (size_t)node * 64 + oct * 8);
            hv[0] = o0;
            hv[1] = o1;
        }
    }
}

extern "C" void kernel_launch(void* const* d_in, const int* in_sizes, int n_in,
                              void* d_out, int out_size, void* d_ws, size_t ws_size,
                              hipStream_t stream) {
    const float* x  = (const float*)d_in[0];
    const int*   ei = (const int*)d_in[1];   // [2*E]: src row, then dst row
    const float* W1 = (const float*)d_in[2];
    const float* b1 = (const float*)d_in[3];
    const float* W2 = (const float*)d_in[4];
    const float* b2 = (const float*)d_in[5];
    const float* Wl = (const float*)d_in[6];
    const float* bl = (const float*)d_in[7];
    float* out = (float*)d_out;

    const int N = N_NODES;
    const int E = N_EDGES;
    const int* src = ei;
    const int* dst = ei + E;

    // workspace: gcursor[NBINS] i32 | dinv[N] f32 | offdeg[N] u32 | binned[NBINS*CAP] u32
    //          | tmp[N*64] f16 | h[N*64] f32
    char* ws = (char*)d_ws;
    size_t off = 0;
    auto align = [](size_t v) { return (v + 511) & ~(size_t)511; };
    int* gcursor         = (int*)(ws + off);          off = align(off + (size_t)NBINS * 4);
    float* dinv          = (float*)(ws + off);        off = align(off + (size_t)N * 4);
    unsigned int* offdeg = (unsigned int*)(ws + off); off = align(off + (size_t)N * 4);
    unsigned int* binned = (unsigned int*)(ws + off); off = align(off + (size_t)NBINS * CAP * 4);
    __half* tmp          = (__half*)(ws + off);       off = align(off + (size_t)N * 64 * 2);
    float* h             = (float*)(ws + off);        off = align(off + (size_t)N * 64 * 4);
    (void)ws_size;

    const int NBLK_GEMM = (N + 63) / 64;  // 1563

    // ---- binned COO build + per-bin CSR (built once, used by both aggregates) ----
    hipMemsetAsync(gcursor, 0, (size_t)NBINS * 4, stream);
    binning_kernel<<<NBLK_BIN, 256, 0, stream>>>(src, dst, gcursor, binned, E);
    csr_kernel<<<NBINS, 256, 0, stream>>>(binned, gcursor, dinv, offdeg);

    // ---- layer 1: tmp = fp16(dinv * (x @ W1)); h = relu(dinv * gather(tmp) + b1) ----
    gemm_kernel<64, true><<<NBLK_GEMM, 256, 0, stream>>>(x, W1, nullptr, dinv, tmp, N);
    aggregate_kernel<<<NBINS, 256, 0, stream>>>(tmp, binned, gcursor, offdeg, dinv, b1, h);

    // ---- layer 2 ----
    gemm_kernel<64, true><<<NBLK_GEMM, 256, 0, stream>>>(h, W2, nullptr, dinv, tmp, N);
    aggregate_kernel<<<NBINS, 256, 0, stream>>>(tmp, binned, gcursor, offdeg, b2 ? dinv : dinv, b2, h);

    // ---- head: out = h @ Wl + bl ----
    gemm_kernel<32, false><<<NBLK_GEMM, 256, 0, stream>>>(h, Wl, bl, nullptr, out, N);
}

// Round 10
// 204.483 us; speedup vs baseline: 1.0756x; 1.0756x over previous
//
#include <hip/hip_runtime.h>
#include <hip/hip_fp16.h>

#define N_NODES 100000
#define N_EDGES 1200000

#define BIN_SHIFT 6
#define NODES_PER_BIN 64                       // 1 << BIN_SHIFT
#define NBINS ((N_NODES + NODES_PER_BIN - 1) >> BIN_SHIFT)   // 1563
#define CAP 1024                               // max edges per bucket (mean 768)
#define EPB 8192                               // edges per binning block
#define NBLK_BIN ((N_EDGES + EPB - 1) / EPB)   // 147

// ---------------- binning: edges -> fixed-stride bucket regions ----------------
// packed word: src (bits 0..16) | (dst & 63) << 17
__global__ void binning_kernel(const int* __restrict__ src, const int* __restrict__ dst,
                               int* __restrict__ gcursor, unsigned int* __restrict__ binned,
                               int E) {
    __shared__ unsigned int stage[EPB];      // 32 KB
    __shared__ unsigned short sbin[EPB];     // 16 KB
    __shared__ unsigned int hist[NBINS];     // ~6.3 KB
    int t = threadIdx.x;
    int e_base = blockIdx.x * EPB;

    for (int b = t; b < NBINS; b += 256) hist[b] = 0;
    __syncthreads();

#pragma unroll
    for (int j = 0; j < EPB / 256; ++j) {
        int idx = e_base + t + j * 256;
        if (idx < E) {
            int s = src[idx];
            int d = dst[idx];
            unsigned int bin = (unsigned int)d >> BIN_SHIFT;
            stage[t + j * 256] = (unsigned int)s | (((unsigned int)d & 63u) << 17);
            sbin[t + j * 256] = (unsigned short)bin;
            atomicAdd(&hist[bin], 1u);
        }
    }
    __syncthreads();

    for (int b = t; b < NBINS; b += 256) {
        unsigned int c = hist[b];
        if (c) hist[b] = (unsigned int)(b * CAP) + (unsigned int)atomicAdd(&gcursor[b], (int)c);
    }
    __syncthreads();

#pragma unroll
    for (int j = 0; j < EPB / 256; ++j) {
        int idx = e_base + t + j * 256;
        if (idx < E) {
            unsigned int bin = sbin[t + j * 256];
            unsigned int pos = atomicAdd(&hist[bin], 1u);
            binned[pos] = stage[t + j * 256];
        }
    }
}

// ---------------- csr: per-bucket degree -> dinv, CSR-sort srcs in place,
//                  offdeg[node] = (local_off << 16) | deg ----------------
__global__ void csr_kernel(unsigned int* __restrict__ binned,
                           const int* __restrict__ gcursor,
                           float* __restrict__ dinv,
                           unsigned int* __restrict__ offdeg) {
    __shared__ unsigned int eLDS[CAP];
    __shared__ unsigned int counts[NODES_PER_BIN];
    __shared__ unsigned int scan[NODES_PER_BIN];
    __shared__ unsigned int offs[NODES_PER_BIN];
    __shared__ unsigned int cur[NODES_PER_BIN];
    int bin = blockIdx.x;
    int t = threadIdx.x;
    int nb = gcursor[bin];
    unsigned int* eb = binned + (size_t)bin * CAP;

    if (t < NODES_PER_BIN) counts[t] = 0;
    __syncthreads();
    for (int i = t; i < nb; i += 256) {
        unsigned int p = eb[i];
        eLDS[i] = p;
        atomicAdd(&counts[p >> 17], 1u);
    }
    __syncthreads();
    if (t < NODES_PER_BIN) scan[t] = counts[t];
    __syncthreads();
    for (int step = 1; step < NODES_PER_BIN; step <<= 1) {
        unsigned int v = 0;
        if (t < NODES_PER_BIN && t >= step) v = scan[t - step];
        __syncthreads();
        if (t < NODES_PER_BIN) scan[t] += v;
        __syncthreads();
    }
    if (t < NODES_PER_BIN) {
        offs[t] = scan[t] - counts[t];
        cur[t] = 0;
    }
    __syncthreads();
    for (int i = t; i < nb; i += 256) {
        unsigned int p = eLDS[i];
        unsigned int l = p >> 17;
        unsigned int pos = offs[l] + atomicAdd(&cur[l], 1u);
        eb[pos] = p & 0x1FFFFu;
    }
    if (t < NODES_PER_BIN) {
        int node = bin * NODES_PER_BIN + t;
        if (node < N_NODES) {
            dinv[node] = rsqrtf((float)(counts[t] + 1u));
            offdeg[node] = (offs[t] << 16) | counts[t];
        }
    }
}

// ---------------- register-tiled skinny GEMM (layer 1 only) ----------------
// tmp[n,64] = fp16( dinv[r] * (X[n,64] @ W[64,64]) )
__global__ __launch_bounds__(256, 4) void gemm1_kernel(const float* __restrict__ X,
                                                       const float* __restrict__ W,
                                                       const float* __restrict__ rowscale,
                                                       __half* __restrict__ Hout, int n) {
    constexpr int COLG = 16;
    constexpr int RGS  = 16;
    constexpr int RPT  = 4;
    constexpr int XPITCH = 17;
    __shared__ float4 sW4[64 * COLG];
    __shared__ float4 sX4[64 * XPITCH];
    int tid = threadIdx.x;

    for (int i = tid; i < 64 * COLG; i += 256) sW4[i] = ((const float4*)W)[i];

    int base_row = blockIdx.x * 64;
    const float4* X4 = (const float4*)X;
    for (int i = tid; i < 64 * 16; i += 256) {
        int r = i >> 4, c = i & 15;
        int gr = base_row + r;
        float4 v = make_float4(0.f, 0.f, 0.f, 0.f);
        if (gr < n) v = X4[(size_t)gr * 16 + c];
        sX4[r * XPITCH + c] = v;
    }
    __syncthreads();

    int cg = tid % COLG;
    int rg = tid / COLG;
    float4 acc[RPT];
#pragma unroll
    for (int r = 0; r < RPT; ++r) acc[r] = make_float4(0.f, 0.f, 0.f, 0.f);

#pragma unroll 2
    for (int k4 = 0; k4 < 16; ++k4) {
        float4 xv[RPT];
#pragma unroll
        for (int r = 0; r < RPT; ++r) xv[r] = sX4[(rg + RGS * r) * XPITCH + k4];
#pragma unroll
        for (int kk = 0; kk < 4; ++kk) {
            float4 w = sW4[(k4 * 4 + kk) * COLG + cg];
#pragma unroll
            for (int r = 0; r < RPT; ++r) {
                float xs = (kk == 0) ? xv[r].x : (kk == 1) ? xv[r].y : (kk == 2) ? xv[r].z : xv[r].w;
                acc[r].x = fmaf(xs, w.x, acc[r].x);
                acc[r].y = fmaf(xs, w.y, acc[r].y);
                acc[r].z = fmaf(xs, w.z, acc[r].z);
                acc[r].w = fmaf(xs, w.w, acc[r].w);
            }
        }
    }

#pragma unroll
    for (int r = 0; r < RPT; ++r) {
        int grow = base_row + rg + RGS * r;
        if (grow < n) {
            float4 v = acc[r];
            float s = rowscale[grow];
            v.x *= s; v.y *= s; v.z *= s; v.w *= s;
            __half2* H2 = (__half2*)Hout;
            size_t idx = (size_t)grow * 32 + 2 * cg;
            H2[idx]     = __floats2half2_rn(v.x, v.y);
            H2[idx + 1] = __floats2half2_rn(v.z, v.w);
        }
    }
}

// ---------------- fused: gather aggregation + epilogue + 64-row GEMM ----------------
// Phase 1 (gather): h_local[v] = relu(dinv[v]*(tmp[v]+sum tmp[src])+gb)  -> LDS
// Phase 2 (gemm):   Hout rows = [rowscale?dinv:1] * (h_local @ W) [+ gbias]
// DOUT=64/HALF_OUT=1 for layer boundary; DOUT=32/fp32+bias for the head.
template<int DOUT, bool HALF_OUT, bool ROWSCALE, bool GEMM_BIAS>
__global__ __launch_bounds__(256, 4) void fused_agg_gemm(
    const __half* __restrict__ tmp,
    const unsigned int* __restrict__ binned,
    const int* __restrict__ gcursor,
    const unsigned int* __restrict__ offdeg,
    const float* __restrict__ dinv,
    const float* __restrict__ gb,        // gather-epilogue bias [64]
    const float* __restrict__ W,         // [64, DOUT]
    const float* __restrict__ gbias,     // gemm bias [DOUT] (if GEMM_BIAS)
    void* __restrict__ Hout) {
    constexpr int COLG = DOUT / 4;       // 16 or 8
    constexpr int RGS  = 256 / COLG;     // 16 or 32
    constexpr int RPT  = 64 / RGS;       // 4 or 2
    constexpr int XPITCH = 17;
    __shared__ unsigned int srcs[CAP];              // 4 KB
    __shared__ unsigned int sOffdeg[NODES_PER_BIN];
    __shared__ float sDinv[NODES_PER_BIN];
    __shared__ float4 sW4[64 * COLG];               // 16 / 8 KB
    __shared__ float4 sH4[64 * XPITCH];             // 17.4 KB

    int bin = blockIdx.x;
    int t = threadIdx.x;
    int nb = gcursor[bin];
    const unsigned int* eb = binned + (size_t)bin * CAP;

    for (int i = t; i < 64 * COLG; i += 256) sW4[i] = ((const float4*)W)[i];
    if (t < NODES_PER_BIN) {
        int node = bin * NODES_PER_BIN + t;
        sOffdeg[t] = (node < N_NODES) ? offdeg[node] : 0;
        sDinv[t]   = (node < N_NODES) ? dinv[node]   : 0.0f;
    }
    for (int i = t; i < nb; i += 256) srcs[i] = eb[i];
    __syncthreads();

    // ---- phase 1: gather (8 threads/node, 16 B slice, one 128 B line per edge) ----
    int oct = t & 7;
    int lnode0 = t >> 3;
    const uint4* tmp16 = (const uint4*)tmp;
    float bb[8];
    {
        const float4 b0 = ((const float4*)gb)[oct * 2];
        const float4 b1 = ((const float4*)gb)[oct * 2 + 1];
        bb[0] = b0.x; bb[1] = b0.y; bb[2] = b0.z; bb[3] = b0.w;
        bb[4] = b1.x; bb[5] = b1.y; bb[6] = b1.z; bb[7] = b1.w;
    }

#pragma unroll
    for (int g = 0; g < 2; ++g) {
        int ln = g * 32 + lnode0;
        int node = bin * NODES_PER_BIN + ln;
        if (node < N_NODES) {
            unsigned int od = sOffdeg[ln];
            int deg = (int)(od & 0xFFFFu);
            int beg = (int)(od >> 16);
            float acc[8];
            {
                uint4 raw = tmp16[(size_t)node * 8 + oct];   // self-loop term
                const __half2* hp = (const __half2*)&raw;
#pragma unroll
                for (int j = 0; j < 4; ++j) {
                    float2 f = __half22float2(hp[j]);
                    acc[2 * j] = f.x; acc[2 * j + 1] = f.y;
                }
            }
            int e = 0;
            for (; e + 3 < deg; e += 4) {       // 4 lines in flight
                unsigned int s0 = srcs[beg + e];
                unsigned int s1 = srcs[beg + e + 1];
                unsigned int s2 = srcs[beg + e + 2];
                unsigned int s3 = srcs[beg + e + 3];
                uint4 r0 = tmp16[(size_t)s0 * 8 + oct];
                uint4 r1 = tmp16[(size_t)s1 * 8 + oct];
                uint4 r2 = tmp16[(size_t)s2 * 8 + oct];
                uint4 r3 = tmp16[(size_t)s3 * 8 + oct];
                const __half2* h0 = (const __half2*)&r0;
                const __half2* h1 = (const __half2*)&r1;
                const __half2* h2 = (const __half2*)&r2;
                const __half2* h3 = (const __half2*)&r3;
#pragma unroll
                for (int j = 0; j < 4; ++j) {
                    float2 f0 = __half22float2(h0[j]);
                    float2 f1 = __half22float2(h1[j]);
                    float2 f2 = __half22float2(h2[j]);
                    float2 f3 = __half22float2(h3[j]);
                    acc[2 * j]     += (f0.x + f1.x) + (f2.x + f3.x);
                    acc[2 * j + 1] += (f0.y + f1.y) + (f2.y + f3.y);
                }
            }
            for (; e < deg; ++e) {
                unsigned int s0 = srcs[beg + e];
                uint4 r0 = tmp16[(size_t)s0 * 8 + oct];
                const __half2* h0 = (const __half2*)&r0;
#pragma unroll
                for (int j = 0; j < 4; ++j) {
                    float2 f0 = __half22float2(h0[j]);
                    acc[2 * j]     += f0.x;
                    acc[2 * j + 1] += f0.y;
                }
            }
            float dv = sDinv[ln];
            float4 o0, o1;
            o0.x = fmaxf(fmaf(dv, acc[0], bb[0]), 0.0f);
            o0.y = fmaxf(fmaf(dv, acc[1], bb[1]), 0.0f);
            o0.z = fmaxf(fmaf(dv, acc[2], bb[2]), 0.0f);
            o0.w = fmaxf(fmaf(dv, acc[3], bb[3]), 0.0f);
            o1.x = fmaxf(fmaf(dv, acc[4], bb[4]), 0.0f);
            o1.y = fmaxf(fmaf(dv, acc[5], bb[5]), 0.0f);
            o1.z = fmaxf(fmaf(dv, acc[6], bb[6]), 0.0f);
            o1.w = fmaxf(fmaf(dv, acc[7], bb[7]), 0.0f);
            sH4[ln * XPITCH + oct * 2]     = o0;
            sH4[ln * XPITCH + oct * 2 + 1] = o1;
        }
    }
    __syncthreads();

    // ---- phase 2: 64-row GEMM from LDS ----
    int cg = t % COLG;
    int rg = t / COLG;
    float4 acc[RPT];
#pragma unroll
    for (int r = 0; r < RPT; ++r) acc[r] = make_float4(0.f, 0.f, 0.f, 0.f);

#pragma unroll 2
    for (int k4 = 0; k4 < 16; ++k4) {
        float4 xv[RPT];
#pragma unroll
        for (int r = 0; r < RPT; ++r) xv[r] = sH4[(rg + RGS * r) * XPITCH + k4];
#pragma unroll
        for (int kk = 0; kk < 4; ++kk) {
            float4 w = sW4[(k4 * 4 + kk) * COLG + cg];
#pragma unroll
            for (int r = 0; r < RPT; ++r) {
                float xs = (kk == 0) ? xv[r].x : (kk == 1) ? xv[r].y : (kk == 2) ? xv[r].z : xv[r].w;
                acc[r].x = fmaf(xs, w.x, acc[r].x);
                acc[r].y = fmaf(xs, w.y, acc[r].y);
                acc[r].z = fmaf(xs, w.z, acc[r].z);
                acc[r].w = fmaf(xs, w.w, acc[r].w);
            }
        }
    }

#pragma unroll
    for (int r = 0; r < RPT; ++r) {
        int ln = rg + RGS * r;
        int node = bin * NODES_PER_BIN + ln;
        if (node < N_NODES) {
            float4 v = acc[r];
            if (ROWSCALE) {
                float s = sDinv[ln];
                v.x *= s; v.y *= s; v.z *= s; v.w *= s;
            }
            if (GEMM_BIAS) {
                float4 bbq = ((const float4*)gbias)[cg];
                v.x += bbq.x; v.y += bbq.y; v.z += bbq.z; v.w += bbq.w;
            }
            if (HALF_OUT) {
                __half2* H2 = (__half2*)Hout;
                size_t idx = (size_t)node * (DOUT / 2) + 2 * cg;
                H2[idx]     = __floats2half2_rn(v.x, v.y);
                H2[idx + 1] = __floats2half2_rn(v.z, v.w);
            } else {
                ((float4*)Hout)[(size_t)node * COLG + cg] = v;
            }
        }
    }
}

extern "C" void kernel_launch(void* const* d_in, const int* in_sizes, int n_in,
                              void* d_out, int out_size, void* d_ws, size_t ws_size,
                              hipStream_t stream) {
    const float* x  = (const float*)d_in[0];
    const int*   ei = (const int*)d_in[1];   // [2*E]: src row, then dst row
    const float* W1 = (const float*)d_in[2];
    const float* b1 = (const float*)d_in[3];
    const float* W2 = (const float*)d_in[4];
    const float* b2 = (const float*)d_in[5];
    const float* Wl = (const float*)d_in[6];
    const float* bl = (const float*)d_in[7];
    float* out = (float*)d_out;

    const int N = N_NODES;
    const int E = N_EDGES;
    const int* src = ei;
    const int* dst = ei + E;

    // workspace: gcursor | dinv | offdeg | binned | tmp (f16) | tmp2 (f16)
    char* ws = (char*)d_ws;
    size_t off = 0;
    auto align = [](size_t v) { return (v + 511) & ~(size_t)511; };
    int* gcursor         = (int*)(ws + off);          off = align(off + (size_t)NBINS * 4);
    float* dinv          = (float*)(ws + off);        off = align(off + (size_t)N * 4);
    unsigned int* offdeg = (unsigned int*)(ws + off); off = align(off + (size_t)N * 4);
    unsigned int* binned = (unsigned int*)(ws + off); off = align(off + (size_t)NBINS * CAP * 4);
    __half* tmp          = (__half*)(ws + off);       off = align(off + (size_t)N * 64 * 2);
    __half* tmp2         = (__half*)(ws + off);       off = align(off + (size_t)N * 64 * 2);
    (void)ws_size;

    const int NBLK_GEMM = (N + 63) / 64;  // 1563

    // ---- topology: binned COO + per-bin CSR + dinv (built once) ----
    hipMemsetAsync(gcursor, 0, (size_t)NBINS * 4, stream);
    binning_kernel<<<NBLK_BIN, 256, 0, stream>>>(src, dst, gcursor, binned, E);
    csr_kernel<<<NBINS, 256, 0, stream>>>(binned, gcursor, dinv, offdeg);

    // ---- layer 1 transform: tmp = fp16(dinv * (x @ W1)) ----
    gemm1_kernel<<<NBLK_GEMM, 256, 0, stream>>>(x, W1, dinv, tmp, N);

    // ---- agg1 + layer-2 transform fused: tmp2 = fp16(dinv * (relu(...b1) @ W2)) ----
    fused_agg_gemm<64, true, true, false><<<NBINS, 256, 0, stream>>>(
        tmp, binned, gcursor, offdeg, dinv, b1, W2, nullptr, tmp2);

    // ---- agg2 + head fused: out = relu(...b2) @ Wl + bl ----
    fused_agg_gemm<32, false, false, true><<<NBINS, 256, 0, stream>>>(
        tmp2, binned, gcursor, offdeg, dinv, b2, Wl, bl, out);
}

// Round 11
// 190.816 us; speedup vs baseline: 1.1526x; 1.0716x over previous
//
#include <hip/hip_runtime.h>
#include <hip/hip_fp16.h>

#define N_NODES 100000
#define N_EDGES 1200000

#define BIN_SHIFT 6
#define NODES_PER_BIN 64                       // 1 << BIN_SHIFT
#define NBINS ((N_NODES + NODES_PER_BIN - 1) >> BIN_SHIFT)   // 1563
#define CAP 1024                               // max edges per bucket (mean 768)
#define EPB 8192                               // edges per binning block
#define NBLK_BIN ((N_EDGES + EPB - 1) / EPB)   // 147
#define NBLK_GEMM ((N_NODES + 63) / 64)        // 1563
// union LDS: binning = 32768+16384+6252 = 55404; gemm1 = 16384+17408 = 33792
#define SMEM_BYTES 55424

// ================= combined binning + gemm1 (independent stages, one dispatch) =================
// blocks [0, NBLK_BIN): bin edges; packed word = src | (dst&63)<<17
// blocks [NBLK_BIN, ...): tmp[n,64] = fp16(X @ W1)   (UNSCALED; gather applies dinv)
__global__ __launch_bounds__(256, 2) void bin_gemm1_kernel(
    const int* __restrict__ src, const int* __restrict__ dst,
    int* __restrict__ gcursor, unsigned int* __restrict__ binned,
    const float* __restrict__ X, const float* __restrict__ W1,
    __half* __restrict__ tmp) {
    __shared__ __align__(16) char smem[SMEM_BYTES];
    int t = threadIdx.x;

    if (blockIdx.x < NBLK_BIN) {
        // ---------------- binning body ----------------
        unsigned int* stage = (unsigned int*)smem;                      // 32 KB
        unsigned short* sbin = (unsigned short*)(smem + EPB * 4);       // 16 KB
        unsigned int* hist = (unsigned int*)(smem + EPB * 4 + EPB * 2); // 6.3 KB
        int e_base = blockIdx.x * EPB;

        for (int b = t; b < NBINS; b += 256) hist[b] = 0;
        __syncthreads();

#pragma unroll
        for (int j = 0; j < EPB / 256; ++j) {
            int idx = e_base + t + j * 256;
            if (idx < N_EDGES) {
                int s = src[idx];
                int d = dst[idx];
                unsigned int bin = (unsigned int)d >> BIN_SHIFT;
                stage[t + j * 256] = (unsigned int)s | (((unsigned int)d & 63u) << 17);
                sbin[t + j * 256] = (unsigned short)bin;
                atomicAdd(&hist[bin], 1u);
            }
        }
        __syncthreads();

        for (int b = t; b < NBINS; b += 256) {
            unsigned int c = hist[b];
            if (c) hist[b] = (unsigned int)(b * CAP) + (unsigned int)atomicAdd(&gcursor[b], (int)c);
        }
        __syncthreads();

#pragma unroll
        for (int j = 0; j < EPB / 256; ++j) {
            int idx = e_base + t + j * 256;
            if (idx < N_EDGES) {
                unsigned int bin = sbin[t + j * 256];
                unsigned int pos = atomicAdd(&hist[bin], 1u);
                binned[pos] = stage[t + j * 256];
            }
        }
    } else {
        // ---------------- gemm1 body (64 rows, register-tiled, all-b128 LDS) ----------------
        constexpr int COLG = 16, RGS = 16, RPT = 4, XPITCH = 17;
        float4* sW4 = (float4*)smem;                    // 16 KB
        float4* sX4 = (float4*)(smem + 64 * COLG * 16); // 17.4 KB

        for (int i = t; i < 64 * COLG; i += 256) sW4[i] = ((const float4*)W1)[i];

        int base_row = (blockIdx.x - NBLK_BIN) * 64;
        const float4* X4 = (const float4*)X;
        for (int i = t; i < 64 * 16; i += 256) {
            int r = i >> 4, c = i & 15;
            int gr = base_row + r;
            float4 v = make_float4(0.f, 0.f, 0.f, 0.f);
            if (gr < N_NODES) v = X4[(size_t)gr * 16 + c];
            sX4[r * XPITCH + c] = v;
        }
        __syncthreads();

        int cg = t % COLG;
        int rg = t / COLG;
        float4 acc[RPT];
#pragma unroll
        for (int r = 0; r < RPT; ++r) acc[r] = make_float4(0.f, 0.f, 0.f, 0.f);

#pragma unroll 2
        for (int k4 = 0; k4 < 16; ++k4) {
            float4 xv[RPT];
#pragma unroll
            for (int r = 0; r < RPT; ++r) xv[r] = sX4[(rg + RGS * r) * XPITCH + k4];
#pragma unroll
            for (int kk = 0; kk < 4; ++kk) {
                float4 w = sW4[(k4 * 4 + kk) * COLG + cg];
#pragma unroll
                for (int r = 0; r < RPT; ++r) {
                    float xs = (kk == 0) ? xv[r].x : (kk == 1) ? xv[r].y : (kk == 2) ? xv[r].z : xv[r].w;
                    acc[r].x = fmaf(xs, w.x, acc[r].x);
                    acc[r].y = fmaf(xs, w.y, acc[r].y);
                    acc[r].z = fmaf(xs, w.z, acc[r].z);
                    acc[r].w = fmaf(xs, w.w, acc[r].w);
                }
            }
        }

#pragma unroll
        for (int r = 0; r < RPT; ++r) {
            int grow = base_row + rg + RGS * r;
            if (grow < N_NODES) {
                float4 v = acc[r];
                __half2* H2 = (__half2*)tmp;
                size_t idx = (size_t)grow * 32 + 2 * cg;
                H2[idx]     = __floats2half2_rn(v.x, v.y);
                H2[idx + 1] = __floats2half2_rn(v.z, v.w);
            }
        }
    }
}

// ---------------- csr: per-bucket degree -> dinv, CSR-sort srcs in place,
//                  offdeg[node] = (local_off << 16) | deg ----------------
__global__ void csr_kernel(unsigned int* __restrict__ binned,
                           const int* __restrict__ gcursor,
                           float* __restrict__ dinv,
                           unsigned int* __restrict__ offdeg) {
    __shared__ unsigned int eLDS[CAP];
    __shared__ unsigned int counts[NODES_PER_BIN];
    __shared__ unsigned int scan[NODES_PER_BIN];
    __shared__ unsigned int offs[NODES_PER_BIN];
    __shared__ unsigned int cur[NODES_PER_BIN];
    int bin = blockIdx.x;
    int t = threadIdx.x;
    int nb = gcursor[bin];
    unsigned int* eb = binned + (size_t)bin * CAP;

    if (t < NODES_PER_BIN) counts[t] = 0;
    __syncthreads();
    for (int i = t; i < nb; i += 256) {
        unsigned int p = eb[i];
        eLDS[i] = p;
        atomicAdd(&counts[p >> 17], 1u);
    }
    __syncthreads();
    if (t < NODES_PER_BIN) scan[t] = counts[t];
    __syncthreads();
    for (int step = 1; step < NODES_PER_BIN; step <<= 1) {
        unsigned int v = 0;
        if (t < NODES_PER_BIN && t >= step) v = scan[t - step];
        __syncthreads();
        if (t < NODES_PER_BIN) scan[t] += v;
        __syncthreads();
    }
    if (t < NODES_PER_BIN) {
        offs[t] = scan[t] - counts[t];
        cur[t] = 0;
    }
    __syncthreads();
    for (int i = t; i < nb; i += 256) {
        unsigned int p = eLDS[i];
        unsigned int l = p >> 17;
        unsigned int pos = offs[l] + atomicAdd(&cur[l], 1u);
        eb[pos] = p & 0x1FFFFu;
    }
    if (t < NODES_PER_BIN) {
        int node = bin * NODES_PER_BIN + t;
        if (node < N_NODES) {
            dinv[node] = rsqrtf((float)(counts[t] + 1u));
            offdeg[node] = (offs[t] << 16) | counts[t];
        }
    }
}

// ---------------- fused: gather aggregation + epilogue + 64-row GEMM ----------------
// Phase 1 (gather): h_local[v] = relu(dinv[v]*(S) + gb) -> LDS, where
//   PRESCALED: S = tmp[v] + sum tmp[src]            (tmp rows pre-scaled by dinv)
//  !PRESCALED: S = dinv[v]*tmp[v] + sum dinv[s]*tmp[s]
// Phase 2 (gemm): Hout rows = [ROWSCALE?dinv:1] * (h_local @ W) [+ gbias]
template<int DOUT, bool HALF_OUT, bool ROWSCALE, bool GEMM_BIAS, bool PRESCALED>
__global__ __launch_bounds__(256, 4) void fused_agg_gemm(
    const __half* __restrict__ tmp,
    const unsigned int* __restrict__ binned,
    const int* __restrict__ gcursor,
    const unsigned int* __restrict__ offdeg,
    const float* __restrict__ dinv,
    const float* __restrict__ gb,        // gather-epilogue bias [64]
    const float* __restrict__ W,         // [64, DOUT]
    const float* __restrict__ gbias,     // gemm bias [DOUT] (if GEMM_BIAS)
    void* __restrict__ Hout) {
    constexpr int COLG = DOUT / 4;       // 16 or 8
    constexpr int RGS  = 256 / COLG;     // 16 or 32
    constexpr int RPT  = 64 / RGS;       // 4 or 2
    constexpr int XPITCH = 17;
    __shared__ unsigned int srcs[CAP];              // 4 KB
    __shared__ unsigned int sOffdeg[NODES_PER_BIN];
    __shared__ float sDinv[NODES_PER_BIN];
    __shared__ float4 sW4[64 * COLG];               // 16 / 8 KB
    __shared__ float4 sH4[64 * XPITCH];             // 17.4 KB

    int bin = blockIdx.x;
    int t = threadIdx.x;
    int nb = gcursor[bin];
    const unsigned int* eb = binned + (size_t)bin * CAP;

    for (int i = t; i < 64 * COLG; i += 256) sW4[i] = ((const float4*)W)[i];
    if (t < NODES_PER_BIN) {
        int node = bin * NODES_PER_BIN + t;
        sOffdeg[t] = (node < N_NODES) ? offdeg[node] : 0;
        sDinv[t]   = (node < N_NODES) ? dinv[node]   : 0.0f;
    }
    for (int i = t; i < nb; i += 256) srcs[i] = eb[i];
    __syncthreads();

    // ---- phase 1: gather (8 threads/node, 16 B slice, one 128 B line per edge) ----
    int oct = t & 7;
    int lnode0 = t >> 3;
    const uint4* tmp16 = (const uint4*)tmp;
    float bb[8];
    {
        const float4 b0 = ((const float4*)gb)[oct * 2];
        const float4 b1 = ((const float4*)gb)[oct * 2 + 1];
        bb[0] = b0.x; bb[1] = b0.y; bb[2] = b0.z; bb[3] = b0.w;
        bb[4] = b1.x; bb[5] = b1.y; bb[6] = b1.z; bb[7] = b1.w;
    }

#pragma unroll
    for (int g = 0; g < 2; ++g) {
        int ln = g * 32 + lnode0;
        int node = bin * NODES_PER_BIN + ln;
        if (node < N_NODES) {
            unsigned int od = sOffdeg[ln];
            int deg = (int)(od & 0xFFFFu);
            int beg = (int)(od >> 16);
            float dv = sDinv[ln];
            float acc[8];
            {
                uint4 raw = tmp16[(size_t)node * 8 + oct];   // self-loop term
                const __half2* hp = (const __half2*)&raw;
                float selfs = PRESCALED ? 1.0f : dv;
#pragma unroll
                for (int j = 0; j < 4; ++j) {
                    float2 f = __half22float2(hp[j]);
                    acc[2 * j] = selfs * f.x; acc[2 * j + 1] = selfs * f.y;
                }
            }
            int e = 0;
            for (; e + 3 < deg; e += 4) {       // 4 lines in flight
                unsigned int s0 = srcs[beg + e];
                unsigned int s1 = srcs[beg + e + 1];
                unsigned int s2 = srcs[beg + e + 2];
                unsigned int s3 = srcs[beg + e + 3];
                float w0 = 1.f, w1 = 1.f, w2 = 1.f, w3 = 1.f;
                if (!PRESCALED) {
                    w0 = dinv[s0]; w1 = dinv[s1]; w2 = dinv[s2]; w3 = dinv[s3];
                }
                uint4 r0 = tmp16[(size_t)s0 * 8 + oct];
                uint4 r1 = tmp16[(size_t)s1 * 8 + oct];
                uint4 r2 = tmp16[(size_t)s2 * 8 + oct];
                uint4 r3 = tmp16[(size_t)s3 * 8 + oct];
                const __half2* h0 = (const __half2*)&r0;
                const __half2* h1 = (const __half2*)&r1;
                const __half2* h2 = (const __half2*)&r2;
                const __half2* h3 = (const __half2*)&r3;
#pragma unroll
                for (int j = 0; j < 4; ++j) {
                    float2 f0 = __half22float2(h0[j]);
                    float2 f1 = __half22float2(h1[j]);
                    float2 f2 = __half22float2(h2[j]);
                    float2 f3 = __half22float2(h3[j]);
                    if (PRESCALED) {
                        acc[2 * j]     += (f0.x + f1.x) + (f2.x + f3.x);
                        acc[2 * j + 1] += (f0.y + f1.y) + (f2.y + f3.y);
                    } else {
                        acc[2 * j]     = fmaf(w0, f0.x, fmaf(w1, f1.x, fmaf(w2, f2.x, fmaf(w3, f3.x, acc[2 * j]))));
                        acc[2 * j + 1] = fmaf(w0, f0.y, fmaf(w1, f1.y, fmaf(w2, f2.y, fmaf(w3, f3.y, acc[2 * j + 1]))));
                    }
                }
            }
            for (; e < deg; ++e) {
                unsigned int s0 = srcs[beg + e];
                float w0 = PRESCALED ? 1.0f : dinv[s0];
                uint4 r0 = tmp16[(size_t)s0 * 8 + oct];
                const __half2* h0 = (const __half2*)&r0;
#pragma unroll
                for (int j = 0; j < 4; ++j) {
                    float2 f0 = __half22float2(h0[j]);
                    acc[2 * j]     = fmaf(w0, f0.x, acc[2 * j]);
                    acc[2 * j + 1] = fmaf(w0, f0.y, acc[2 * j + 1]);
                }
            }
            float4 o0, o1;
            o0.x = fmaxf(fmaf(dv, acc[0], bb[0]), 0.0f);
            o0.y = fmaxf(fmaf(dv, acc[1], bb[1]), 0.0f);
            o0.z = fmaxf(fmaf(dv, acc[2], bb[2]), 0.0f);
            o0.w = fmaxf(fmaf(dv, acc[3], bb[3]), 0.0f);
            o1.x = fmaxf(fmaf(dv, acc[4], bb[4]), 0.0f);
            o1.y = fmaxf(fmaf(dv, acc[5], bb[5]), 0.0f);
            o1.z = fmaxf(fmaf(dv, acc[6], bb[6]), 0.0f);
            o1.w = fmaxf(fmaf(dv, acc[7], bb[7]), 0.0f);
            sH4[ln * XPITCH + oct * 2]     = o0;
            sH4[ln * XPITCH + oct * 2 + 1] = o1;
        }
    }
    __syncthreads();

    // ---- phase 2: 64-row GEMM from LDS ----
    int cg = t % COLG;
    int rg = t / COLG;
    float4 acc[RPT];
#pragma unroll
    for (int r = 0; r < RPT; ++r) acc[r] = make_float4(0.f, 0.f, 0.f, 0.f);

#pragma unroll 2
    for (int k4 = 0; k4 < 16; ++k4) {
        float4 xv[RPT];
#pragma unroll
        for (int r = 0; r < RPT; ++r) xv[r] = sH4[(rg + RGS * r) * XPITCH + k4];
#pragma unroll
        for (int kk = 0; kk < 4; ++kk) {
            float4 w = sW4[(k4 * 4 + kk) * COLG + cg];
#pragma unroll
            for (int r = 0; r < RPT; ++r) {
                float xs = (kk == 0) ? xv[r].x : (kk == 1) ? xv[r].y : (kk == 2) ? xv[r].z : xv[r].w;
                acc[r].x = fmaf(xs, w.x, acc[r].x);
                acc[r].y = fmaf(xs, w.y, acc[r].y);
                acc[r].z = fmaf(xs, w.z, acc[r].z);
                acc[r].w = fmaf(xs, w.w, acc[r].w);
            }
        }
    }

#pragma unroll
    for (int r = 0; r < RPT; ++r) {
        int ln = rg + RGS * r;
        int node = bin * NODES_PER_BIN + ln;
        if (node < N_NODES) {
            float4 v = acc[r];
            if (ROWSCALE) {
                float s = sDinv[ln];
                v.x *= s; v.y *= s; v.z *= s; v.w *= s;
            }
            if (GEMM_BIAS) {
                float4 bbq = ((const float4*)gbias)[cg];
                v.x += bbq.x; v.y += bbq.y; v.z += bbq.z; v.w += bbq.w;
            }
            if (HALF_OUT) {
                __half2* H2 = (__half2*)Hout;
                size_t idx = (size_t)node * (DOUT / 2) + 2 * cg;
                H2[idx]     = __floats2half2_rn(v.x, v.y);
                H2[idx + 1] = __floats2half2_rn(v.z, v.w);
            } else {
                ((float4*)Hout)[(size_t)node * COLG + cg] = v;
            }
        }
    }
}

extern "C" void kernel_launch(void* const* d_in, const int* in_sizes, int n_in,
                              void* d_out, int out_size, void* d_ws, size_t ws_size,
                              hipStream_t stream) {
    const float* x  = (const float*)d_in[0];
    const int*   ei = (const int*)d_in[1];   // [2*E]: src row, then dst row
    const float* W1 = (const float*)d_in[2];
    const float* b1 = (const float*)d_in[3];
    const float* W2 = (const float*)d_in[4];
    const float* b2 = (const float*)d_in[5];
    const float* Wl = (const float*)d_in[6];
    const float* bl = (const float*)d_in[7];
    float* out = (float*)d_out;

    const int* src = ei;
    const int* dst = ei + N_EDGES;

    // workspace: gcursor | dinv | offdeg | binned | tmp (f16) | tmp2 (f16)
    char* ws = (char*)d_ws;
    size_t off = 0;
    auto align = [](size_t v) { return (v + 511) & ~(size_t)511; };
    int* gcursor         = (int*)(ws + off);          off = align(off + (size_t)NBINS * 4);
    float* dinv          = (float*)(ws + off);        off = align(off + (size_t)N_NODES * 4);
    unsigned int* offdeg = (unsigned int*)(ws + off); off = align(off + (size_t)N_NODES * 4);
    unsigned int* binned = (unsigned int*)(ws + off); off = align(off + (size_t)NBINS * CAP * 4);
    __half* tmp          = (__half*)(ws + off);       off = align(off + (size_t)N_NODES * 64 * 2);
    __half* tmp2         = (__half*)(ws + off);       off = align(off + (size_t)N_NODES * 64 * 2);
    (void)ws_size;

    // ---- front end: zero cursors; then binning and layer-1 transform OVERLAPPED ----
    hipMemsetAsync(gcursor, 0, (size_t)NBINS * 4, stream);
    bin_gemm1_kernel<<<NBLK_BIN + NBLK_GEMM, 256, 0, stream>>>(
        src, dst, gcursor, binned, x, W1, tmp);

    // ---- per-bin CSR + dinv (built once, reused by both fused stages) ----
    csr_kernel<<<NBINS, 256, 0, stream>>>(binned, gcursor, dinv, offdeg);

    // ---- agg1 (applies dinv[src] per edge) + layer-2 transform: tmp2 = fp16(dinv*(relu(..b1)@W2)) ----
    fused_agg_gemm<64, true, true, false, false><<<NBINS, 256, 0, stream>>>(
        tmp, binned, gcursor, offdeg, dinv, b1, W2, nullptr, tmp2);

    // ---- agg2 (tmp2 pre-scaled) + head: out = relu(..b2) @ Wl + bl ----
    fused_agg_gemm<32, false, false, true, true><<<NBINS, 256, 0, stream>>>(
        tmp2, binned, gcursor, offdeg, dinv, b2, Wl, bl, out);
}

// Round 12
// 189.137 us; speedup vs baseline: 1.1629x; 1.0089x over previous
//
#include <hip/hip_runtime.h>
#include <hip/hip_fp16.h>

#define N_NODES 100000
#define N_EDGES 1200000

#define BIN_SHIFT 6
#define NODES_PER_BIN 64                       // 1 << BIN_SHIFT
#define NBINS ((N_NODES + NODES_PER_BIN - 1) >> BIN_SHIFT)   // 1563
#define CAP 1024                               // max edges per bucket (mean 768)
#define EPB 8192                               // edges per binning block
#define NBLK_BIN ((N_EDGES + EPB - 1) / EPB)   // 147
#define NBLK_GEMM ((N_NODES + 63) / 64)        // 1563
// union LDS: binning = 32768+16384+6252 = 55404; gemm1 = 16384+17408 = 33792
#define SMEM_BYTES 55424

// ================= combined binning + gemm1 (independent stages, one dispatch) =================
// blocks [0, NBLK_BIN): bin edges; packed word = src | (dst&63)<<17
// blocks [NBLK_BIN, ...): tmp[n,64] = fp16(X @ W1)   (UNSCALED; gather applies dinv)
__global__ __launch_bounds__(256, 2) void bin_gemm1_kernel(
    const int* __restrict__ src, const int* __restrict__ dst,
    int* __restrict__ gcursor, unsigned int* __restrict__ binned,
    const float* __restrict__ X, const float* __restrict__ W1,
    __half* __restrict__ tmp) {
    __shared__ __align__(16) char smem[SMEM_BYTES];
    int t = threadIdx.x;

    if (blockIdx.x < NBLK_BIN) {
        // ---------------- binning body ----------------
        unsigned int* stage = (unsigned int*)smem;                      // 32 KB
        unsigned short* sbin = (unsigned short*)(smem + EPB * 4);       // 16 KB
        unsigned int* hist = (unsigned int*)(smem + EPB * 4 + EPB * 2); // 6.3 KB
        int e_base = blockIdx.x * EPB;

        for (int b = t; b < NBINS; b += 256) hist[b] = 0;
        __syncthreads();

#pragma unroll
        for (int j = 0; j < EPB / 256; ++j) {
            int idx = e_base + t + j * 256;
            if (idx < N_EDGES) {
                int s = src[idx];
                int d = dst[idx];
                unsigned int bin = (unsigned int)d >> BIN_SHIFT;
                stage[t + j * 256] = (unsigned int)s | (((unsigned int)d & 63u) << 17);
                sbin[t + j * 256] = (unsigned short)bin;
                atomicAdd(&hist[bin], 1u);
            }
        }
        __syncthreads();

        for (int b = t; b < NBINS; b += 256) {
            unsigned int c = hist[b];
            if (c) hist[b] = (unsigned int)(b * CAP) + (unsigned int)atomicAdd(&gcursor[b], (int)c);
        }
        __syncthreads();

#pragma unroll
        for (int j = 0; j < EPB / 256; ++j) {
            int idx = e_base + t + j * 256;
            if (idx < N_EDGES) {
                unsigned int bin = sbin[t + j * 256];
                unsigned int pos = atomicAdd(&hist[bin], 1u);
                binned[pos] = stage[t + j * 256];
            }
        }
    } else {
        // ---------------- gemm1 body (64 rows, register-tiled, all-b128 LDS) ----------------
        constexpr int COLG = 16, RGS = 16, RPT = 4, XPITCH = 17;
        float4* sW4 = (float4*)smem;                    // 16 KB
        float4* sX4 = (float4*)(smem + 64 * COLG * 16); // 17.4 KB

        for (int i = t; i < 64 * COLG; i += 256) sW4[i] = ((const float4*)W1)[i];

        int base_row = (blockIdx.x - NBLK_BIN) * 64;
        const float4* X4 = (const float4*)X;
        for (int i = t; i < 64 * 16; i += 256) {
            int r = i >> 4, c = i & 15;
            int gr = base_row + r;
            float4 v = make_float4(0.f, 0.f, 0.f, 0.f);
            if (gr < N_NODES) v = X4[(size_t)gr * 16 + c];
            sX4[r * XPITCH + c] = v;
        }
        __syncthreads();

        int cg = t % COLG;
        int rg = t / COLG;
        float4 acc[RPT];
#pragma unroll
        for (int r = 0; r < RPT; ++r) acc[r] = make_float4(0.f, 0.f, 0.f, 0.f);

#pragma unroll 2
        for (int k4 = 0; k4 < 16; ++k4) {
            float4 xv[RPT];
#pragma unroll
            for (int r = 0; r < RPT; ++r) xv[r] = sX4[(rg + RGS * r) * XPITCH + k4];
#pragma unroll
            for (int kk = 0; kk < 4; ++kk) {
                float4 w = sW4[(k4 * 4 + kk) * COLG + cg];
#pragma unroll
                for (int r = 0; r < RPT; ++r) {
                    float xs = (kk == 0) ? xv[r].x : (kk == 1) ? xv[r].y : (kk == 2) ? xv[r].z : xv[r].w;
                    acc[r].x = fmaf(xs, w.x, acc[r].x);
                    acc[r].y = fmaf(xs, w.y, acc[r].y);
                    acc[r].z = fmaf(xs, w.z, acc[r].z);
                    acc[r].w = fmaf(xs, w.w, acc[r].w);
                }
            }
        }

#pragma unroll
        for (int r = 0; r < RPT; ++r) {
            int grow = base_row + rg + RGS * r;
            if (grow < N_NODES) {
                float4 v = acc[r];
                __half2* H2 = (__half2*)tmp;
                size_t idx = (size_t)grow * 32 + 2 * cg;
                H2[idx]     = __floats2half2_rn(v.x, v.y);
                H2[idx + 1] = __floats2half2_rn(v.z, v.w);
            }
        }
    }
}

// ---------------- csr: per-bucket degree -> dinv, CSR-sort srcs in place,
//                  offdeg[node] = (local_off << 16) | deg ----------------
__global__ void csr_kernel(unsigned int* __restrict__ binned,
                           const int* __restrict__ gcursor,
                           float* __restrict__ dinv,
                           unsigned int* __restrict__ offdeg) {
    __shared__ unsigned int eLDS[CAP];
    __shared__ unsigned int counts[NODES_PER_BIN];
    __shared__ unsigned int scan[NODES_PER_BIN];
    __shared__ unsigned int offs[NODES_PER_BIN];
    __shared__ unsigned int cur[NODES_PER_BIN];
    int bin = blockIdx.x;
    int t = threadIdx.x;
    int nb = gcursor[bin];
    unsigned int* eb = binned + (size_t)bin * CAP;

    if (t < NODES_PER_BIN) counts[t] = 0;
    __syncthreads();
    for (int i = t; i < nb; i += 256) {
        unsigned int p = eb[i];
        eLDS[i] = p;
        atomicAdd(&counts[p >> 17], 1u);
    }
    __syncthreads();
    if (t < NODES_PER_BIN) scan[t] = counts[t];
    __syncthreads();
    for (int step = 1; step < NODES_PER_BIN; step <<= 1) {
        unsigned int v = 0;
        if (t < NODES_PER_BIN && t >= step) v = scan[t - step];
        __syncthreads();
        if (t < NODES_PER_BIN) scan[t] += v;
        __syncthreads();
    }
    if (t < NODES_PER_BIN) {
        offs[t] = scan[t] - counts[t];
        cur[t] = 0;
    }
    __syncthreads();
    for (int i = t; i < nb; i += 256) {
        unsigned int p = eLDS[i];
        unsigned int l = p >> 17;
        unsigned int pos = offs[l] + atomicAdd(&cur[l], 1u);
        eb[pos] = p & 0x1FFFFu;
    }
    if (t < NODES_PER_BIN) {
        int node = bin * NODES_PER_BIN + t;
        if (node < N_NODES) {
            dinv[node] = rsqrtf((float)(counts[t] + 1u));
            offdeg[node] = (offs[t] << 16) | counts[t];
        }
    }
}

// ---------------- fused: gather aggregation + epilogue + 64-row GEMM ----------------
// Phase 1 (gather): h_local[v] = relu(dinv[v]*(S) + gb) -> LDS, where
//   PRESCALED: S = tmp[v] + sum tmp[src]            (tmp rows pre-scaled by dinv)
//  !PRESCALED: S = dinv[v]*tmp[v] + sum dinv[s]*tmp[s]
// Phase 2 (gemm): Hout rows = [ROWSCALE?dinv:1] * (h_local @ W) [+ gbias]
// W is read directly from global (L1-resident, shared per-CU) -> LDS ~22.3 KB
// -> 6 blocks/CU (launch_bounds(256,6)): 1536 of 1563 blocks co-resident, no tail wave.
template<int DOUT, bool HALF_OUT, bool ROWSCALE, bool GEMM_BIAS, bool PRESCALED>
__global__ __launch_bounds__(256, 6) void fused_agg_gemm(
    const __half* __restrict__ tmp,
    const unsigned int* __restrict__ binned,
    const int* __restrict__ gcursor,
    const unsigned int* __restrict__ offdeg,
    const float* __restrict__ dinv,
    const float* __restrict__ gb,        // gather-epilogue bias [64]
    const float* __restrict__ W,         // [64, DOUT]
    const float* __restrict__ gbias,     // gemm bias [DOUT] (if GEMM_BIAS)
    void* __restrict__ Hout) {
    constexpr int COLG = DOUT / 4;       // 16 or 8
    constexpr int RGS  = 256 / COLG;     // 16 or 32
    constexpr int RPT  = 64 / RGS;       // 4 or 2
    constexpr int XPITCH = 17;
    __shared__ unsigned int srcs[CAP];              // 4 KB
    __shared__ unsigned int sOffdeg[NODES_PER_BIN];
    __shared__ float sDinv[NODES_PER_BIN];
    __shared__ float4 sH4[64 * XPITCH];             // 17.4 KB

    int bin = blockIdx.x;
    int t = threadIdx.x;
    int nb = gcursor[bin];
    const unsigned int* eb = binned + (size_t)bin * CAP;

    if (t < NODES_PER_BIN) {
        int node = bin * NODES_PER_BIN + t;
        sOffdeg[t] = (node < N_NODES) ? offdeg[node] : 0;
        sDinv[t]   = (node < N_NODES) ? dinv[node]   : 0.0f;
    }
    for (int i = t; i < nb; i += 256) srcs[i] = eb[i];
    __syncthreads();

    // ---- phase 1: gather (8 threads/node, 16 B slice, one 128 B line per edge) ----
    int oct = t & 7;
    int lnode0 = t >> 3;
    const uint4* tmp16 = (const uint4*)tmp;
    float bb[8];
    {
        const float4 b0 = ((const float4*)gb)[oct * 2];
        const float4 b1 = ((const float4*)gb)[oct * 2 + 1];
        bb[0] = b0.x; bb[1] = b0.y; bb[2] = b0.z; bb[3] = b0.w;
        bb[4] = b1.x; bb[5] = b1.y; bb[6] = b1.z; bb[7] = b1.w;
    }

#pragma unroll
    for (int g = 0; g < 2; ++g) {
        int ln = g * 32 + lnode0;
        int node = bin * NODES_PER_BIN + ln;
        if (node < N_NODES) {
            unsigned int od = sOffdeg[ln];
            int deg = (int)(od & 0xFFFFu);
            int beg = (int)(od >> 16);
            float dv = sDinv[ln];
            float acc[8];
            {
                uint4 raw = tmp16[(size_t)node * 8 + oct];   // self-loop term
                const __half2* hp = (const __half2*)&raw;
                float selfs = PRESCALED ? 1.0f : dv;
#pragma unroll
                for (int j = 0; j < 4; ++j) {
                    float2 f = __half22float2(hp[j]);
                    acc[2 * j] = selfs * f.x; acc[2 * j + 1] = selfs * f.y;
                }
            }
            int e = 0;
            for (; e + 3 < deg; e += 4) {       // 4 lines in flight
                unsigned int s0 = srcs[beg + e];
                unsigned int s1 = srcs[beg + e + 1];
                unsigned int s2 = srcs[beg + e + 2];
                unsigned int s3 = srcs[beg + e + 3];
                float w0 = 1.f, w1 = 1.f, w2 = 1.f, w3 = 1.f;
                if (!PRESCALED) {
                    w0 = dinv[s0]; w1 = dinv[s1]; w2 = dinv[s2]; w3 = dinv[s3];
                }
                uint4 r0 = tmp16[(size_t)s0 * 8 + oct];
                uint4 r1 = tmp16[(size_t)s1 * 8 + oct];
                uint4 r2 = tmp16[(size_t)s2 * 8 + oct];
                uint4 r3 = tmp16[(size_t)s3 * 8 + oct];
                const __half2* h0 = (const __half2*)&r0;
                const __half2* h1 = (const __half2*)&r1;
                const __half2* h2 = (const __half2*)&r2;
                const __half2* h3 = (const __half2*)&r3;
#pragma unroll
                for (int j = 0; j < 4; ++j) {
                    float2 f0 = __half22float2(h0[j]);
                    float2 f1 = __half22float2(h1[j]);
                    float2 f2 = __half22float2(h2[j]);
                    float2 f3 = __half22float2(h3[j]);
                    if (PRESCALED) {
                        acc[2 * j]     += (f0.x + f1.x) + (f2.x + f3.x);
                        acc[2 * j + 1] += (f0.y + f1.y) + (f2.y + f3.y);
                    } else {
                        acc[2 * j]     = fmaf(w0, f0.x, fmaf(w1, f1.x, fmaf(w2, f2.x, fmaf(w3, f3.x, acc[2 * j]))));
                        acc[2 * j + 1] = fmaf(w0, f0.y, fmaf(w1, f1.y, fmaf(w2, f2.y, fmaf(w3, f3.y, acc[2 * j + 1]))));
                    }
                }
            }
            for (; e < deg; ++e) {
                unsigned int s0 = srcs[beg + e];
                float w0 = PRESCALED ? 1.0f : dinv[s0];
                uint4 r0 = tmp16[(size_t)s0 * 8 + oct];
                const __half2* h0 = (const __half2*)&r0;
#pragma unroll
                for (int j = 0; j < 4; ++j) {
                    float2 f0 = __half22float2(h0[j]);
                    acc[2 * j]     = fmaf(w0, f0.x, acc[2 * j]);
                    acc[2 * j + 1] = fmaf(w0, f0.y, acc[2 * j + 1]);
                }
            }
            float4 o0, o1;
            o0.x = fmaxf(fmaf(dv, acc[0], bb[0]), 0.0f);
            o0.y = fmaxf(fmaf(dv, acc[1], bb[1]), 0.0f);
            o0.z = fmaxf(fmaf(dv, acc[2], bb[2]), 0.0f);
            o0.w = fmaxf(fmaf(dv, acc[3], bb[3]), 0.0f);
            o1.x = fmaxf(fmaf(dv, acc[4], bb[4]), 0.0f);
            o1.y = fmaxf(fmaf(dv, acc[5], bb[5]), 0.0f);
            o1.z = fmaxf(fmaf(dv, acc[6], bb[6]), 0.0f);
            o1.w = fmaxf(fmaf(dv, acc[7], bb[7]), 0.0f);
            sH4[ln * XPITCH + oct * 2]     = o0;
            sH4[ln * XPITCH + oct * 2 + 1] = o1;
        }
    }
    __syncthreads();

    // ---- phase 2: 64-row GEMM from LDS (X) and global (W, L1-hot) ----
    int cg = t % COLG;
    int rg = t / COLG;
    const float4* W4 = (const float4*)W;
    float4 acc[RPT];
#pragma unroll
    for (int r = 0; r < RPT; ++r) acc[r] = make_float4(0.f, 0.f, 0.f, 0.f);

#pragma unroll 2
    for (int k4 = 0; k4 < 16; ++k4) {
        float4 xv[RPT];
#pragma unroll
        for (int r = 0; r < RPT; ++r) xv[r] = sH4[(rg + RGS * r) * XPITCH + k4];
#pragma unroll
        for (int kk = 0; kk < 4; ++kk) {
            float4 w = W4[(k4 * 4 + kk) * COLG + cg];
#pragma unroll
            for (int r = 0; r < RPT; ++r) {
                float xs = (kk == 0) ? xv[r].x : (kk == 1) ? xv[r].y : (kk == 2) ? xv[r].z : xv[r].w;
                acc[r].x = fmaf(xs, w.x, acc[r].x);
                acc[r].y = fmaf(xs, w.y, acc[r].y);
                acc[r].z = fmaf(xs, w.z, acc[r].z);
                acc[r].w = fmaf(xs, w.w, acc[r].w);
            }
        }
    }

#pragma unroll
    for (int r = 0; r < RPT; ++r) {
        int ln = rg + RGS * r;
        int node = bin * NODES_PER_BIN + ln;
        if (node < N_NODES) {
            float4 v = acc[r];
            if (ROWSCALE) {
                float s = sDinv[ln];
                v.x *= s; v.y *= s; v.z *= s; v.w *= s;
            }
            if (GEMM_BIAS) {
                float4 bbq = ((const float4*)gbias)[cg];
                v.x += bbq.x; v.y += bbq.y; v.z += bbq.z; v.w += bbq.w;
            }
            if (HALF_OUT) {
                __half2* H2 = (__half2*)Hout;
                size_t idx = (size_t)node * (DOUT / 2) + 2 * cg;
                H2[idx]     = __floats2half2_rn(v.x, v.y);
                H2[idx + 1] = __floats2half2_rn(v.z, v.w);
            } else {
                ((float4*)Hout)[(size_t)node * COLG + cg] = v;
            }
        }
    }
}

extern "C" void kernel_launch(void* const* d_in, const int* in_sizes, int n_in,
                              void* d_out, int out_size, void* d_ws, size_t ws_size,
                              hipStream_t stream) {
    const float* x  = (const float*)d_in[0];
    const int*   ei = (const int*)d_in[1];   // [2*E]: src row, then dst row
    const float* W1 = (const float*)d_in[2];
    const float* b1 = (const float*)d_in[3];
    const float* W2 = (const float*)d_in[4];
    const float* b2 = (const float*)d_in[5];
    const float* Wl = (const float*)d_in[6];
    const float* bl = (const float*)d_in[7];
    float* out = (float*)d_out;

    const int* src = ei;
    const int* dst = ei + N_EDGES;

    // workspace: gcursor | dinv | offdeg | binned | tmp (f16) | tmp2 (f16)
    char* ws = (char*)d_ws;
    size_t off = 0;
    auto align = [](size_t v) { return (v + 511) & ~(size_t)511; };
    int* gcursor         = (int*)(ws + off);          off = align(off + (size_t)NBINS * 4);
    float* dinv          = (float*)(ws + off);        off = align(off + (size_t)N_NODES * 4);
    unsigned int* offdeg = (unsigned int*)(ws + off); off = align(off + (size_t)N_NODES * 4);
    unsigned int* binned = (unsigned int*)(ws + off); off = align(off + (size_t)NBINS * CAP * 4);
    __half* tmp          = (__half*)(ws + off);       off = align(off + (size_t)N_NODES * 64 * 2);
    __half* tmp2         = (__half*)(ws + off);       off = align(off + (size_t)N_NODES * 64 * 2);
    (void)ws_size;

    // ---- front end: zero cursors; then binning and layer-1 transform OVERLAPPED ----
    hipMemsetAsync(gcursor, 0, (size_t)NBINS * 4, stream);
    bin_gemm1_kernel<<<NBLK_BIN + NBLK_GEMM, 256, 0, stream>>>(
        src, dst, gcursor, binned, x, W1, tmp);

    // ---- per-bin CSR + dinv (built once, reused by both fused stages) ----
    csr_kernel<<<NBINS, 256, 0, stream>>>(binned, gcursor, dinv, offdeg);

    // ---- agg1 (applies dinv[src] per edge) + layer-2 transform: tmp2 = fp16(dinv*(relu(..b1)@W2)) ----
    fused_agg_gemm<64, true, true, false, false><<<NBINS, 256, 0, stream>>>(
        tmp, binned, gcursor, offdeg, dinv, b1, W2, nullptr, tmp2);

    // ---- agg2 (tmp2 pre-scaled) + head: out = relu(..b2) @ Wl + bl ----
    fused_agg_gemm<32, false, false, true, true><<<NBINS, 256, 0, stream>>>(
        tmp2, binned, gcursor, offdeg, dinv, b2, Wl, bl, out);
}